// Round 4
// baseline (141.384 us; speedup 1.0000x reference)
//
#include <hip/hip_runtime.h>
#include <math.h>

#define KOBJ 512
#define KTW 8               // packed row (32 B): xh[4] (8 fp16), s2, w_rep, w_att, pad
#define TKP 128             // objects per pairs-tile
#define NTILEP (KOBJ / TKP) // 4
#define MPREP 256           // prep blocks -> partial-table rows
#define GB 64               // gather blocks (8 objects each)

typedef _Float16 half2_t __attribute__((ext_vector_type(2)));

#define AGS(p, v) __hip_atomic_store((p), (v), __ATOMIC_RELAXED, __HIP_MEMORY_SCOPE_AGENT)
#define AGL(p)    __hip_atomic_load((p), __ATOMIC_RELAXED, __HIP_MEMORY_SCOPE_AGENT)

__device__ __forceinline__ float wave_red_f(float v) {
  #pragma unroll
  for (int off = 32; off > 0; off >>= 1) v += __shfl_down(v, off, 64);
  return v;
}

// fast atanh(b)^2 + 1 ; b in (0, 0.96]
__device__ __forceinline__ float q_of_beta(float b) {
  float a = 0.5f * __logf((1.f + b) / (1.f - b));
  return fmaf(a, a, 1.f);
}

// acc + y.h0*k.h0 + ... over 8 fp16 components, fp32 accumulate.
// Fixed op order -> bit-identical between in-loop and own-undo paths.
__device__ __forceinline__ float dot8h(uint4 kx, const uint* y, float acc) {
#if __has_builtin(__builtin_amdgcn_fdot2)
  acc = __builtin_amdgcn_fdot2(__builtin_bit_cast(half2_t, y[0]),
                               __builtin_bit_cast(half2_t, kx.x), acc, false);
  acc = __builtin_amdgcn_fdot2(__builtin_bit_cast(half2_t, y[1]),
                               __builtin_bit_cast(half2_t, kx.y), acc, false);
  acc = __builtin_amdgcn_fdot2(__builtin_bit_cast(half2_t, y[2]),
                               __builtin_bit_cast(half2_t, kx.z), acc, false);
  acc = __builtin_amdgcn_fdot2(__builtin_bit_cast(half2_t, y[3]),
                               __builtin_bit_cast(half2_t, kx.w), acc, false);
#else
  const uint kk[4] = {kx.x, kx.y, kx.z, kx.w};
  #pragma unroll
  for (int c = 0; c < 4; c++) {
    half2_t a = __builtin_bit_cast(half2_t, y[c]);
    half2_t b = __builtin_bit_cast(half2_t, kk[c]);
    acc = fmaf((float)a.x, (float)b.x, acc);
    acc = fmaf((float)a.y, (float)b.y, acc);
  }
#endif
  return acc;
}

// ---------------------------------------------------------------------------
// Pass 1: 256 blocks x 256 threads (<=2 hits/thread). LDS-aggregated
// per-object argmax(q)/counts -> per-block partial rows; payload losses
// block-reduced; packed per-hit records (SoA):
//   hry[i] = 8 fp16 of (-2*x_i)      (16 B)
//   hrm[i] = { |x|^2, q, oid, 0 }    (16 B)
// ---------------------------------------------------------------------------
__global__ __launch_bounds__(256) void
k_prep(const float* __restrict__ beta, const float* __restrict__ x,
       const int* __restrict__ oid,
       const float* __restrict__ energy, const float* __restrict__ eph,
       const float* __restrict__ mom, const float* __restrict__ mph,
       const float* __restrict__ logits, const int* __restrict__ pid,
       unsigned long long* __restrict__ amax_part,
       unsigned* __restrict__ cnt_part,
       float* __restrict__ scal_part,
       uint4* __restrict__ hry, uint4* __restrict__ hrm,
       unsigned* __restrict__ done_cnt, int n) {
  __shared__ unsigned long long lmax[KOBJ];
  __shared__ unsigned lcnt[KOBJ];
  if (blockIdx.x == 0 && threadIdx.x == 0) *done_cnt = 0u;  // visible to pass 3 at kernel boundary
  for (int t = threadIdx.x; t < KOBJ; t += 256) { lmax[t] = 0ull; lcnt[t] = 0u; }
  __syncthreads();

  const float4* xp = (const float4*)x;
  float e_t = 0.f, p_t = 0.f, pid_t = 0.f, noise_t = 0.f, ncnt = 0.f, mcnt = 0.f;
  for (int i = blockIdx.x * 256 + threadIdx.x; i < n; i += MPREP * 256) {
    float b = beta[i];
    int o = oid[i];
    float q = q_of_beta(b);                  // needed for ALL hits (repulsion)
    float4 xa = xp[2 * (size_t)i];
    float4 xb = xp[2 * (size_t)i + 1];
    float xi[8] = {xa.x, xa.y, xa.z, xa.w, xb.x, xb.y, xb.z, xb.w};
    float s = 0.f;
    #pragma unroll
    for (int c = 0; c < 8; c++) s = fmaf(xi[c], xi[c], s);
    uint4 r0;
    {
      half2_t h0 = { (_Float16)(-2.f * xi[0]), (_Float16)(-2.f * xi[1]) };
      half2_t h1 = { (_Float16)(-2.f * xi[2]), (_Float16)(-2.f * xi[3]) };
      half2_t h2 = { (_Float16)(-2.f * xi[4]), (_Float16)(-2.f * xi[5]) };
      half2_t h3 = { (_Float16)(-2.f * xi[6]), (_Float16)(-2.f * xi[7]) };
      r0.x = __builtin_bit_cast(uint, h0);
      r0.y = __builtin_bit_cast(uint, h1);
      r0.z = __builtin_bit_cast(uint, h2);
      r0.w = __builtin_bit_cast(uint, h3);
    }
    uint4 r1 = { __float_as_uint(s), __float_as_uint(q), (uint)o, 0u };
    hry[i] = r0;
    hrm[i] = r1;

    if (o > 0) {
      // pack (q bits | ~i): max-q wins, ties -> smallest index (argmax semantics)
      unsigned long long key = ((unsigned long long)__float_as_uint(q) << 32)
                             | (unsigned long long)(unsigned)(~(unsigned)i);
      atomicMax(&lmax[o - 1], key);
      atomicAdd(&lcnt[o - 1], 1u);
      mcnt += 1.f;
      float de = energy[i] - eph[i];
      e_t = fmaf(de, de, e_t);
      float p0 = mom[3*i+0] - mph[3*i+0];
      float p1 = mom[3*i+1] - mph[3*i+1];
      float p2 = mom[3*i+2] - mph[3*i+2];
      p_t = fmaf(p0, p0, p_t); p_t = fmaf(p1, p1, p_t); p_t = fmaf(p2, p2, p_t);
      const float* lg = logits + 6*i;
      float l0=lg[0], l1=lg[1], l2=lg[2], l3=lg[3], l4=lg[4], l5=lg[5];
      float mx = fmaxf(fmaxf(fmaxf(l0,l1),fmaxf(l2,l3)), fmaxf(l4,l5));
      float sm = __expf(l0-mx)+__expf(l1-mx)+__expf(l2-mx)
               + __expf(l3-mx)+__expf(l4-mx)+__expf(l5-mx);
      int pc = pid[i];
      float lp = (pc==0)?l0:(pc==1)?l1:(pc==2)?l2:(pc==3)?l3:(pc==4)?l4:l5;
      pid_t += mx + __logf(sm) - lp;
    } else {
      noise_t += b;
      ncnt += 1.f;
    }
  }
  __syncthreads();

  for (int t = threadIdx.x; t < KOBJ; t += 256) {
    amax_part[(size_t)blockIdx.x * KOBJ + t] = lmax[t];
    cnt_part[(size_t)blockIdx.x * KOBJ + t]  = lcnt[t];
  }

  float vals[6] = {e_t, p_t, pid_t, noise_t, ncnt, mcnt};
  #pragma unroll
  for (int j = 0; j < 6; j++) vals[j] = wave_red_f(vals[j]);
  __shared__ float sred[4][6];
  int w = threadIdx.x >> 6, l = threadIdx.x & 63;
  if (l == 0) {
    #pragma unroll
    for (int j = 0; j < 6; j++) sred[w][j] = vals[j];
  }
  __syncthreads();
  if (threadIdx.x == 0) {
    #pragma unroll
    for (int j = 0; j < 6; j++)
      scal_part[blockIdx.x * 8 + j] = sred[0][j]+sred[1][j]+sred[2][j]+sred[3][j];
  }
}

// ---------------------------------------------------------------------------
// Pass 2: 64 blocks x 256 threads, 8 objects/block. Reduce the 256 partial
// rows ONCE into the global packed table ktab[512(+2 pad)][8] and per-block
// coward partials. Kills the 16x-redundant gather that was 90 MB of L3
// traffic in the fused version.
// ---------------------------------------------------------------------------
__global__ __launch_bounds__(256) void
k_gather(const float* __restrict__ x, const float* __restrict__ beta,
         const unsigned long long* __restrict__ amax_part,
         const unsigned* __restrict__ cnt_part,
         uint* __restrict__ ktab, float* __restrict__ cow_part, int n) {
  __shared__ unsigned long long skey[32][8];
  __shared__ unsigned scnt[32][8];
  const int o = threadIdx.x & 7, seg = threadIdx.x >> 3;
  const int k = blockIdx.x * 8 + o;

  unsigned long long key = 0ull;
  unsigned cnt = 0u;
  for (int m = seg; m < MPREP; m += 32) {
    unsigned long long km = amax_part[(size_t)m * KOBJ + k];
    key = (km > key) ? km : key;
    cnt += cnt_part[(size_t)m * KOBJ + k];
  }
  skey[seg][o] = key;
  scnt[seg][o] = cnt;
  __syncthreads();
  for (int s = 16; s > 0; s >>= 1) {
    if (seg < s) {
      unsigned long long k2 = skey[seg + s][o];
      if (k2 > skey[seg][o]) skey[seg][o] = k2;
      scnt[seg][o] += scnt[seg + s][o];
    }
    __syncthreads();
  }

  float cowv = 0.f;
  if (threadIdx.x < 8) {                 // seg==0: one thread per object
    key = skey[0][o];
    cnt = scnt[0][o];
    unsigned idx = ~(unsigned)(key & 0xffffffffull);
    float q_k = __uint_as_float((unsigned)(key >> 32));
    const float4* xp = (const float4*)x;
    float4 xa = xp[2 * (size_t)idx];
    float4 xb = xp[2 * (size_t)idx + 1];
    float xv[8] = {xa.x, xa.y, xa.z, xa.w, xb.x, xb.y, xb.z, xb.w};
    float s2 = 0.f;
    #pragma unroll
    for (int c = 0; c < 8; c++) s2 = fmaf(xv[c], xv[c], s2);
    uint* kt = ktab + (size_t)k * KTW;
    #pragma unroll
    for (int c = 0; c < 4; c++) {
      half2_t hp = { (_Float16)xv[2*c], (_Float16)xv[2*c+1] };
      kt[c] = __builtin_bit_cast(uint, hp);
    }
    kt[4] = __float_as_uint(s2);
    kt[5] = __float_as_uint(q_k / ((float)(n - (int)cnt) + 1e-9f));  // w_rep
    kt[6] = __float_as_uint(q_k / ((float)cnt + 1e-9f));             // w_att
    kt[7] = 0u;
    cowv = 1.f - beta[idx];
  }
  if (threadIdx.x < 64) {                // wave 0: sum 8 coward values
    cowv = wave_red_f(cowv);
    if (threadIdx.x == 0) cow_part[blockIdx.x] = cowv;
  }
  // zero the 2 pad rows read by the pairs pipeline's overshoot
  if (blockIdx.x == 0 && threadIdx.x >= 64 && threadIdx.x < 80)
    ktab[(size_t)KOBJ * KTW + (threadIdx.x - 64)] = 0u;
}

// ---------------------------------------------------------------------------
// Pass 3 (hot): grid (469 hit-blocks x 4 tiles of 128 objects). One hit per
// thread; table rows read at wave-uniform addresses straight from global
// (scalar-cache / L1 broadcast), software-pipelined 2 rows ahead. No LDS in
// the hot loop, no redundant partial-table reads. Records read once per tile
// (4x total = 15 MB, vs 61 MB before). Own-object undo bit-exact (same
// global bytes, same dot8h op order). Last-finishing block finalizes.
// ---------------------------------------------------------------------------
__global__ __launch_bounds__(256, 4) void
k_pairs(const uint4* __restrict__ hry, const uint4* __restrict__ hrm,
        const uint* __restrict__ ktab,
        const float* __restrict__ scal_part, const float* __restrict__ cow_part,
        float* __restrict__ pairs_part, unsigned* __restrict__ done_cnt,
        float* __restrict__ out, int n) {
  __shared__ float sredu[4][10];
  __shared__ unsigned slast;
  const int tid = threadIdx.x;
  const int w = tid >> 6, l = tid & 63;
  const int tile0 = blockIdx.y * TKP;
  const int i = blockIdx.x * 256 + tid;
  const int nblk = gridDim.x * gridDim.y;
  const int bid = blockIdx.y * gridDim.x + blockIdx.x;

  uint yh[4];
  float thr, bh, qi;
  int own;
  if (i < n) {
    uint4 ra = hry[i];
    uint4 rb = hrm[i];
    yh[0] = ra.x; yh[1] = ra.y; yh[2] = ra.z; yh[3] = ra.w;
    float s = __uint_as_float(rb.x);
    bh = s;
    thr = 1.f - s;            // accept iff d2' < thr  (d2 = d2' + |xi|^2 < 1)
    qi = __uint_as_float(rb.y);
    own = (int)rb.z - 1 - tile0;
  } else {
    yh[0] = yh[1] = yh[2] = yh[3] = 0u;
    bh = 0.f; thr = -1e30f; qi = 0.f; own = -1;
  }

  // rows as pairs of uint4; index is wave-uniform -> scalar loads expected
  const uint4* kt4 = (const uint4*)ktab + (size_t)tile0 * 2;
  float att = 0.f, rep = 0.f, nrep = 0.f;
  uint4 a0 = kt4[0], b0 = kt4[1];
  uint4 a1 = kt4[2], b1 = kt4[3];
  #pragma unroll 2
  for (int r = 0; r < TKP; r += 2) {
    uint4 na0 = kt4[2*r + 4], nb0 = kt4[2*r + 5];   // overshoots into pad rows at the end
    uint4 na1 = kt4[2*r + 6], nb1 = kt4[2*r + 7];
    {
      float s2 = __uint_as_float(b0.x);
      float wr = __uint_as_float(b0.y);
      float dp = dot8h(a0, yh, s2);                 // s2 - 2*xi.xk
      if (dp < thr) {
        float d2 = dp + bh;
        float dist = sqrtf(fmaxf(d2, 1e-12f));
        rep = fmaf(qi * (1.f - dist), wr, rep);
        nrep += 1.f;
      }
    }
    {
      float s2 = __uint_as_float(b1.x);
      float wr = __uint_as_float(b1.y);
      float dp = dot8h(a1, yh, s2);
      if (dp < thr) {
        float d2 = dp + bh;
        float dist = sqrtf(fmaxf(d2, 1e-12f));
        rep = fmaf(qi * (1.f - dist), wr, rep);
        nrep += 1.f;
      }
    }
    a0 = na0; b0 = nb0; a1 = na1; b1 = nb1;
  }

  // own-object: attractive term + bit-exact undo of in-loop repulsive term
  if (own >= 0 && own < TKP) {
    uint4 ka = kt4[2*own];
    uint4 kb = kt4[2*own + 1];
    float s2 = __uint_as_float(kb.x);
    float wr = __uint_as_float(kb.y);
    float wa = __uint_as_float(kb.z);
    float dp = dot8h(ka, yh, s2);          // identical op order -> same bits
    float d2 = dp + bh;
    att = fmaf(qi * fmaxf(d2, 0.f), wa, att);
    if (dp < thr) {
      float dist = sqrtf(fmaxf(d2, 1e-12f));
      rep = fmaf(-qi * (1.f - dist), wr, rep);
      nrep -= 1.f;
    }
  }

  att = wave_red_f(att);
  rep = wave_red_f(rep);
  nrep = wave_red_f(nrep);
  if (l == 0) { sredu[w][0] = att; sredu[w][1] = rep; sredu[w][2] = nrep; }
  __syncthreads();
  if (tid == 0) {
    AGS(&pairs_part[bid * 4 + 0], sredu[0][0]+sredu[1][0]+sredu[2][0]+sredu[3][0]);
    AGS(&pairs_part[bid * 4 + 1], sredu[0][1]+sredu[1][1]+sredu[2][1]+sredu[3][1]);
    AGS(&pairs_part[bid * 4 + 2], sredu[0][2]+sredu[1][2]+sredu[2][2]+sredu[3][2]);
    // release-RMW orders the scoped stores above; acquire side pairs with it
    slast = __hip_atomic_fetch_add(done_cnt, 1u, __ATOMIC_ACQ_REL,
                                   __HIP_MEMORY_SCOPE_AGENT);
  }
  __syncthreads();

  // ---- Finalize: last block only ----
  if (slast == (unsigned)(nblk - 1)) {
    float v[10] = {0,0,0,0,0,0,0,0,0,0};  // att,rep,nrep,e,p,pid,noise,ncnt,mcnt,cow
    for (int b2 = tid; b2 < nblk; b2 += 256) {
      v[0] += AGL(&pairs_part[b2 * 4 + 0]);
      v[1] += AGL(&pairs_part[b2 * 4 + 1]);
      v[2] += AGL(&pairs_part[b2 * 4 + 2]);
    }
    for (int m = tid; m < MPREP; m += 256) {
      #pragma unroll
      for (int j = 0; j < 6; j++) v[3 + j] += scal_part[m * 8 + j];
    }
    for (int g = tid; g < GB; g += 256) v[9] += cow_part[g];
    #pragma unroll
    for (int j = 0; j < 10; j++) v[j] = wave_red_f(v[j]);
    __syncthreads();                      // sredu reuse
    if (l == 0) {
      #pragma unroll
      for (int j = 0; j < 10; j++) sredu[w][j] = v[j];
    }
    __syncthreads();
    if (tid == 0) {
      float t10[10];
      #pragma unroll
      for (int j = 0; j < 10; j++)
        t10[j] = sredu[0][j]+sredu[1][j]+sredu[2][j]+sredu[3][j];
      float v_att  = t10[0] / (float)KOBJ;
      float v_rep  = t10[1] / (float)KOBJ;
      float n_rep  = t10[2];
      float l_cow  = t10[9] / (float)KOBJ;
      float l_noise = t10[6] / t10[7];
      float oc = v_att + v_rep + l_cow + l_noise;
      float nm = t10[8];
      float e_loss  = t10[3] / nm;
      float p_loss  = t10[4] / (nm * 3.f);
      float pid_loss = t10[5] / nm;
      out[0] = v_att;
      out[1] = v_rep;
      out[2] = l_cow;
      out[3] = l_noise;
      out[4] = n_rep;
      out[5] = oc;
      out[6] = e_loss;
      out[7] = p_loss;
      out[8] = pid_loss;
      out[9] = oc + e_loss + p_loss + pid_loss;
    }
  }
}

extern "C" void kernel_launch(void* const* d_in, const int* in_sizes, int n_in,
                              void* d_out, int out_size, void* d_ws, size_t ws_size,
                              hipStream_t stream) {
  const float* beta   = (const float*)d_in[0];
  const float* x      = (const float*)d_in[1];
  const int*   oid    = (const int*)d_in[2];
  const float* energy = (const float*)d_in[3];
  const float* eph    = (const float*)d_in[4];
  const float* mom    = (const float*)d_in[5];
  const float* mph    = (const float*)d_in[6];
  const float* logits = (const float*)d_in[7];
  const int*   pid    = (const int*)d_in[8];
  float* outp = (float*)d_out;
  const int n = in_sizes[0];
  const int nch = (n + 255) / 256;          // 469 hit-blocks
  const int nblk_tot = nch * NTILEP;        // 1876

  char* base = (char*)d_ws;
  size_t off = 0;
  uint*  ktab       = (uint*)(base + off);  off += (size_t)(KOBJ + 2) * KTW * 4;
  float* cow_part   = (float*)(base + off); off += (size_t)GB * 4;
  float* pairs_part = (float*)(base + off); off += (size_t)nblk_tot * 4 * 4;
  float* scal_part  = (float*)(base + off); off += (size_t)MPREP * 8 * 4;
  unsigned* done_cnt = (unsigned*)(base + off); off += 256;
  off = (off + 255) & ~(size_t)255;
  unsigned long long* amax_part = (unsigned long long*)(base + off); off += (size_t)MPREP * KOBJ * 8;
  unsigned* cnt_part = (unsigned*)(base + off);                      off += (size_t)MPREP * KOBJ * 4;
  off = (off + 255) & ~(size_t)255;
  uint4* hry = (uint4*)(base + off); off += (size_t)nch * 256 * 16;
  uint4* hrm = (uint4*)(base + off); off += (size_t)nch * 256 * 16;

  k_prep<<<MPREP, 256, 0, stream>>>(beta, x, oid, energy, eph, mom, mph, logits, pid,
                                    amax_part, cnt_part, scal_part, hry, hrm,
                                    done_cnt, n);
  k_gather<<<GB, 256, 0, stream>>>(x, beta, amax_part, cnt_part, ktab, cow_part, n);
  k_pairs<<<dim3(nch, NTILEP), 256, 0, stream>>>(hry, hrm, ktab, scal_part, cow_part,
                                                 pairs_part, done_cnt, outp, n);
}

// Round 5
// 112.777 us; speedup vs baseline: 1.2537x; 1.2537x over previous
//
#include <hip/hip_runtime.h>
#include <math.h>

#define KOBJ 512
#define KTW 8               // packed row (32 B): xh[4] (8 fp16), s2, w_rep, w_att, pad
#define TK 32               // objects per pairs-tile (LDS-staged)
#define NTILE (KOBJ / TK)   // 16
#define HB 8                // hits per thread (register blocking)
#define HCH (256 * HB)      // 2048 hits per block (x-dim)
#define MPREP 256           // prep blocks -> partial-table rows
#define GB 64               // gather blocks (8 objects each)

typedef _Float16 half2_t __attribute__((ext_vector_type(2)));

#define AGS(p, v) __hip_atomic_store((p), (v), __ATOMIC_RELAXED, __HIP_MEMORY_SCOPE_AGENT)
#define AGL(p)    __hip_atomic_load((p), __ATOMIC_RELAXED, __HIP_MEMORY_SCOPE_AGENT)

__device__ __forceinline__ float wave_red_f(float v) {
  #pragma unroll
  for (int off = 32; off > 0; off >>= 1) v += __shfl_down(v, off, 64);
  return v;
}

// fast atanh(b)^2 + 1 ; b in (0, 0.96]
__device__ __forceinline__ float q_of_beta(float b) {
  float a = 0.5f * __logf((1.f + b) / (1.f - b));
  return fmaf(a, a, 1.f);
}

// acc + y.h0*k.h0 + ... over 8 fp16 components, fp32 accumulate.
// Fixed op order -> bit-identical between in-loop and own-undo paths.
__device__ __forceinline__ float dot8h(uint4 kx, const uint* y, float acc) {
#if __has_builtin(__builtin_amdgcn_fdot2)
  acc = __builtin_amdgcn_fdot2(__builtin_bit_cast(half2_t, y[0]),
                               __builtin_bit_cast(half2_t, kx.x), acc, false);
  acc = __builtin_amdgcn_fdot2(__builtin_bit_cast(half2_t, y[1]),
                               __builtin_bit_cast(half2_t, kx.y), acc, false);
  acc = __builtin_amdgcn_fdot2(__builtin_bit_cast(half2_t, y[2]),
                               __builtin_bit_cast(half2_t, kx.z), acc, false);
  acc = __builtin_amdgcn_fdot2(__builtin_bit_cast(half2_t, y[3]),
                               __builtin_bit_cast(half2_t, kx.w), acc, false);
#else
  const uint kk[4] = {kx.x, kx.y, kx.z, kx.w};
  #pragma unroll
  for (int c = 0; c < 4; c++) {
    half2_t a = __builtin_bit_cast(half2_t, y[c]);
    half2_t b = __builtin_bit_cast(half2_t, kk[c]);
    acc = fmaf((float)a.x, (float)b.x, acc);
    acc = fmaf((float)a.y, (float)b.y, acc);
  }
#endif
  return acc;
}

// ---------------------------------------------------------------------------
// Pass 1: 256 blocks x 256 threads (<=2 hits/thread). LDS-aggregated
// per-object argmax(q)/counts -> per-block partial rows; payload losses
// block-reduced; packed per-hit records (SoA):
//   hry[i] = 8 fp16 of (-2*x_i)      (16 B)
//   hrm[i] = { |x|^2, q, oid, 0 }    (16 B)
// ---------------------------------------------------------------------------
__global__ __launch_bounds__(256) void
k_prep(const float* __restrict__ beta, const float* __restrict__ x,
       const int* __restrict__ oid,
       const float* __restrict__ energy, const float* __restrict__ eph,
       const float* __restrict__ mom, const float* __restrict__ mph,
       const float* __restrict__ logits, const int* __restrict__ pid,
       unsigned long long* __restrict__ amax_part,
       unsigned* __restrict__ cnt_part,
       float* __restrict__ scal_part,
       uint4* __restrict__ hry, uint4* __restrict__ hrm,
       unsigned* __restrict__ done_cnt, int n) {
  __shared__ unsigned long long lmax[KOBJ];
  __shared__ unsigned lcnt[KOBJ];
  if (blockIdx.x == 0 && threadIdx.x == 0) *done_cnt = 0u;  // visible to pass 3 at kernel boundary
  for (int t = threadIdx.x; t < KOBJ; t += 256) { lmax[t] = 0ull; lcnt[t] = 0u; }
  __syncthreads();

  const float4* xp = (const float4*)x;
  float e_t = 0.f, p_t = 0.f, pid_t = 0.f, noise_t = 0.f, ncnt = 0.f, mcnt = 0.f;
  for (int i = blockIdx.x * 256 + threadIdx.x; i < n; i += MPREP * 256) {
    float b = beta[i];
    int o = oid[i];
    float q = q_of_beta(b);                  // needed for ALL hits (repulsion)
    float4 xa = xp[2 * (size_t)i];
    float4 xb = xp[2 * (size_t)i + 1];
    float xi[8] = {xa.x, xa.y, xa.z, xa.w, xb.x, xb.y, xb.z, xb.w};
    float s = 0.f;
    #pragma unroll
    for (int c = 0; c < 8; c++) s = fmaf(xi[c], xi[c], s);
    uint4 r0;
    {
      half2_t h0 = { (_Float16)(-2.f * xi[0]), (_Float16)(-2.f * xi[1]) };
      half2_t h1 = { (_Float16)(-2.f * xi[2]), (_Float16)(-2.f * xi[3]) };
      half2_t h2 = { (_Float16)(-2.f * xi[4]), (_Float16)(-2.f * xi[5]) };
      half2_t h3 = { (_Float16)(-2.f * xi[6]), (_Float16)(-2.f * xi[7]) };
      r0.x = __builtin_bit_cast(uint, h0);
      r0.y = __builtin_bit_cast(uint, h1);
      r0.z = __builtin_bit_cast(uint, h2);
      r0.w = __builtin_bit_cast(uint, h3);
    }
    uint4 r1 = { __float_as_uint(s), __float_as_uint(q), (uint)o, 0u };
    hry[i] = r0;
    hrm[i] = r1;

    if (o > 0) {
      // pack (q bits | ~i): max-q wins, ties -> smallest index (argmax semantics)
      unsigned long long key = ((unsigned long long)__float_as_uint(q) << 32)
                             | (unsigned long long)(unsigned)(~(unsigned)i);
      atomicMax(&lmax[o - 1], key);
      atomicAdd(&lcnt[o - 1], 1u);
      mcnt += 1.f;
      float de = energy[i] - eph[i];
      e_t = fmaf(de, de, e_t);
      float p0 = mom[3*i+0] - mph[3*i+0];
      float p1 = mom[3*i+1] - mph[3*i+1];
      float p2 = mom[3*i+2] - mph[3*i+2];
      p_t = fmaf(p0, p0, p_t); p_t = fmaf(p1, p1, p_t); p_t = fmaf(p2, p2, p_t);
      const float* lg = logits + 6*i;
      float l0=lg[0], l1=lg[1], l2=lg[2], l3=lg[3], l4=lg[4], l5=lg[5];
      float mx = fmaxf(fmaxf(fmaxf(l0,l1),fmaxf(l2,l3)), fmaxf(l4,l5));
      float sm = __expf(l0-mx)+__expf(l1-mx)+__expf(l2-mx)
               + __expf(l3-mx)+__expf(l4-mx)+__expf(l5-mx);
      int pc = pid[i];
      float lp = (pc==0)?l0:(pc==1)?l1:(pc==2)?l2:(pc==3)?l3:(pc==4)?l4:l5;
      pid_t += mx + __logf(sm) - lp;
    } else {
      noise_t += b;
      ncnt += 1.f;
    }
  }
  __syncthreads();

  for (int t = threadIdx.x; t < KOBJ; t += 256) {
    amax_part[(size_t)blockIdx.x * KOBJ + t] = lmax[t];
    cnt_part[(size_t)blockIdx.x * KOBJ + t]  = lcnt[t];
  }

  float vals[6] = {e_t, p_t, pid_t, noise_t, ncnt, mcnt};
  #pragma unroll
  for (int j = 0; j < 6; j++) vals[j] = wave_red_f(vals[j]);
  __shared__ float sred[4][6];
  int w = threadIdx.x >> 6, l = threadIdx.x & 63;
  if (l == 0) {
    #pragma unroll
    for (int j = 0; j < 6; j++) sred[w][j] = vals[j];
  }
  __syncthreads();
  if (threadIdx.x == 0) {
    #pragma unroll
    for (int j = 0; j < 6; j++)
      scal_part[blockIdx.x * 8 + j] = sred[0][j]+sred[1][j]+sred[2][j]+sred[3][j];
  }
}

// ---------------------------------------------------------------------------
// Pass 2: 64 blocks x 256 threads, 8 objects/block. Reduce the 256 partial
// rows ONCE into the global packed table ktab[512][8] + per-block coward
// partials.
// ---------------------------------------------------------------------------
__global__ __launch_bounds__(256) void
k_gather(const float* __restrict__ x, const float* __restrict__ beta,
         const unsigned long long* __restrict__ amax_part,
         const unsigned* __restrict__ cnt_part,
         uint* __restrict__ ktab, float* __restrict__ cow_part, int n) {
  __shared__ unsigned long long skey[32][8];
  __shared__ unsigned scnt[32][8];
  const int o = threadIdx.x & 7, seg = threadIdx.x >> 3;
  const int k = blockIdx.x * 8 + o;

  unsigned long long key = 0ull;
  unsigned cnt = 0u;
  for (int m = seg; m < MPREP; m += 32) {
    unsigned long long km = amax_part[(size_t)m * KOBJ + k];
    key = (km > key) ? km : key;
    cnt += cnt_part[(size_t)m * KOBJ + k];
  }
  skey[seg][o] = key;
  scnt[seg][o] = cnt;
  __syncthreads();
  for (int s = 16; s > 0; s >>= 1) {
    if (seg < s) {
      unsigned long long k2 = skey[seg + s][o];
      if (k2 > skey[seg][o]) skey[seg][o] = k2;
      scnt[seg][o] += scnt[seg + s][o];
    }
    __syncthreads();
  }

  float cowv = 0.f;
  if (threadIdx.x < 8) {                 // seg==0: one thread per object
    key = skey[0][o];
    cnt = scnt[0][o];
    unsigned idx = ~(unsigned)(key & 0xffffffffull);
    float q_k = __uint_as_float((unsigned)(key >> 32));
    const float4* xp = (const float4*)x;
    float4 xa = xp[2 * (size_t)idx];
    float4 xb = xp[2 * (size_t)idx + 1];
    float xv[8] = {xa.x, xa.y, xa.z, xa.w, xb.x, xb.y, xb.z, xb.w};
    float s2 = 0.f;
    #pragma unroll
    for (int c = 0; c < 8; c++) s2 = fmaf(xv[c], xv[c], s2);
    uint* kt = ktab + (size_t)k * KTW;
    #pragma unroll
    for (int c = 0; c < 4; c++) {
      half2_t hp = { (_Float16)xv[2*c], (_Float16)xv[2*c+1] };
      kt[c] = __builtin_bit_cast(uint, hp);
    }
    kt[4] = __float_as_uint(s2);
    kt[5] = __float_as_uint(q_k / ((float)(n - (int)cnt) + 1e-9f));  // w_rep
    kt[6] = __float_as_uint(q_k / ((float)cnt + 1e-9f));             // w_att
    kt[7] = 0u;
    cowv = 1.f - beta[idx];
  }
  if (threadIdx.x < 64) {                // wave 0: sum 8 coward values
    cowv = wave_red_f(cowv);
    if (threadIdx.x == 0) cow_part[blockIdx.x] = cowv;
  }
}

// ---------------------------------------------------------------------------
// Pass 3 (hot): grid (59 hit-chunks x 16 tiles = 944 blocks). HB=8 hits per
// thread in registers (from precomputed records); 32-row tile staged in LDS
// (row fetch amortized over 8 hits, broadcast return path). Fast path per
// row: 32 fdot2 + 8 cmp, one wave-level branch; sqrt/hinge/counters only in
// the ~5%-taken slow path (accept density ~1e-4 -> P(any of 512 pairs) ~5%).
// Own-object undo bit-exact (same LDS bytes, same dot8h op order).
// Last-finishing block finalizes via device-scope atomics.
// ---------------------------------------------------------------------------
__global__ __launch_bounds__(256, 4) void
k_pairs(const uint4* __restrict__ hry, const uint4* __restrict__ hrm,
        const uint* __restrict__ ktab,
        const float* __restrict__ scal_part, const float* __restrict__ cow_part,
        float* __restrict__ pairs_part, unsigned* __restrict__ done_cnt,
        float* __restrict__ out, int n) {
  __shared__ __align__(16) uint skt[(TK + 1) * KTW];  // 32 rows + zero pad row
  __shared__ float sredu[4][10];
  __shared__ unsigned slast;
  const int tid = threadIdx.x;
  const int w = tid >> 6, l = tid & 63;
  const int tile0 = blockIdx.y * TK;
  const int hbase = blockIdx.x * HCH;
  const int nblk = gridDim.x * gridDim.y;
  const int bid = blockIdx.y * gridDim.x + blockIdx.x;

  skt[tid] = ktab[(size_t)tile0 * KTW + tid];   // 256 words = whole tile
  if (tid < KTW) skt[TK * KTW + tid] = 0u;      // pad row for prefetch overshoot
  __syncthreads();

  // per-hit state from packed records
  uint yh[HB][4];
  float thr[HB], bh[HB], qi[HB];
  int own[HB];
  #pragma unroll
  for (int h = 0; h < HB; h++) {
    int i = hbase + h * 256 + tid;
    if (i < n) {
      uint4 ra = hry[i];
      uint4 rb = hrm[i];
      yh[h][0] = ra.x; yh[h][1] = ra.y; yh[h][2] = ra.z; yh[h][3] = ra.w;
      float s = __uint_as_float(rb.x);
      bh[h] = s;
      thr[h] = 1.f - s;     // accept iff d2' < thr  (d2 = d2' + |xi|^2 < 1)
      qi[h] = __uint_as_float(rb.y);
      own[h] = (int)rb.z - 1 - tile0;
    } else {
      #pragma unroll
      for (int c = 0; c < 4; c++) yh[h][c] = 0u;
      bh[h] = 0.f;
      thr[h] = -1e30f;               // never accept
      qi[h] = 0.f;
      own[h] = -1;
    }
  }

  float att = 0.f, rep = 0.f, nrep = 0.f;
  const uint4* skt4 = (const uint4*)skt;     // row r = skt4[2r], skt4[2r+1]
  uint4 ka = skt4[0], kb = skt4[1];
  #pragma unroll 2
  for (int r = 0; r < TK; r++) {
    uint4 na = skt4[2*r + 2];                // prefetch next row (pad at r=TK-1)
    uint4 nb = skt4[2*r + 3];
    float s2 = __uint_as_float(kb.x);
    float wr = __uint_as_float(kb.y);
    float dp[HB];
    #pragma unroll
    for (int h = 0; h < HB; h++) dp[h] = dot8h(ka, yh[h], s2);  // s2 - 2*xi.xk
    bool any = false;
    #pragma unroll
    for (int h = 0; h < HB; h++) any = any | (dp[h] < thr[h]);
    if (any) {                               // wave-branch, ~5% taken
      #pragma unroll
      for (int h = 0; h < HB; h++) {
        if (dp[h] < thr[h]) {                // d2 < 1
          float d2 = dp[h] + bh[h];
          float dist = sqrtf(fmaxf(d2, 1e-12f));
          rep = fmaf(qi[h] * (1.f - dist), wr, rep);
          nrep += 1.f;
        }
      }
    }
    ka = na; kb = nb;
  }

  // own-object: attractive term + bit-exact undo of in-loop repulsive term
  #pragma unroll
  for (int h = 0; h < HB; h++) {
    int ko = own[h];
    if (ko >= 0 && ko < TK) {
      uint4 oa = skt4[2*ko];
      uint4 ob = skt4[2*ko + 1];
      float s2 = __uint_as_float(ob.x);
      float wr = __uint_as_float(ob.y);
      float wa = __uint_as_float(ob.z);
      float dp = dot8h(oa, yh[h], s2);       // identical op order -> same bits
      float d2 = dp + bh[h];
      att = fmaf(qi[h] * fmaxf(d2, 0.f), wa, att);
      if (dp < thr[h]) {
        float dist = sqrtf(fmaxf(d2, 1e-12f));
        rep = fmaf(-qi[h] * (1.f - dist), wr, rep);
        nrep -= 1.f;
      }
    }
  }

  att = wave_red_f(att);
  rep = wave_red_f(rep);
  nrep = wave_red_f(nrep);
  if (l == 0) { sredu[w][0] = att; sredu[w][1] = rep; sredu[w][2] = nrep; }
  __syncthreads();
  if (tid == 0) {
    AGS(&pairs_part[bid * 4 + 0], sredu[0][0]+sredu[1][0]+sredu[2][0]+sredu[3][0]);
    AGS(&pairs_part[bid * 4 + 1], sredu[0][1]+sredu[1][1]+sredu[2][1]+sredu[3][1]);
    AGS(&pairs_part[bid * 4 + 2], sredu[0][2]+sredu[1][2]+sredu[2][2]+sredu[3][2]);
    // release-RMW orders the scoped stores above; acquire side pairs with it
    slast = __hip_atomic_fetch_add(done_cnt, 1u, __ATOMIC_ACQ_REL,
                                   __HIP_MEMORY_SCOPE_AGENT);
  }
  __syncthreads();

  // ---- Finalize: last block only ----
  if (slast == (unsigned)(nblk - 1)) {
    float v[10] = {0,0,0,0,0,0,0,0,0,0};  // att,rep,nrep,e,p,pid,noise,ncnt,mcnt,cow
    for (int b2 = tid; b2 < nblk; b2 += 256) {
      v[0] += AGL(&pairs_part[b2 * 4 + 0]);
      v[1] += AGL(&pairs_part[b2 * 4 + 1]);
      v[2] += AGL(&pairs_part[b2 * 4 + 2]);
    }
    for (int m = tid; m < MPREP; m += 256) {
      #pragma unroll
      for (int j = 0; j < 6; j++) v[3 + j] += scal_part[m * 8 + j];
    }
    for (int g = tid; g < GB; g += 256) v[9] += cow_part[g];
    #pragma unroll
    for (int j = 0; j < 10; j++) v[j] = wave_red_f(v[j]);
    __syncthreads();                      // sredu reuse
    if (l == 0) {
      #pragma unroll
      for (int j = 0; j < 10; j++) sredu[w][j] = v[j];
    }
    __syncthreads();
    if (tid == 0) {
      float t10[10];
      #pragma unroll
      for (int j = 0; j < 10; j++)
        t10[j] = sredu[0][j]+sredu[1][j]+sredu[2][j]+sredu[3][j];
      float v_att  = t10[0] / (float)KOBJ;
      float v_rep  = t10[1] / (float)KOBJ;
      float n_rep  = t10[2];
      float l_cow  = t10[9] / (float)KOBJ;
      float l_noise = t10[6] / t10[7];
      float oc = v_att + v_rep + l_cow + l_noise;
      float nm = t10[8];
      float e_loss  = t10[3] / nm;
      float p_loss  = t10[4] / (nm * 3.f);
      float pid_loss = t10[5] / nm;
      out[0] = v_att;
      out[1] = v_rep;
      out[2] = l_cow;
      out[3] = l_noise;
      out[4] = n_rep;
      out[5] = oc;
      out[6] = e_loss;
      out[7] = p_loss;
      out[8] = pid_loss;
      out[9] = oc + e_loss + p_loss + pid_loss;
    }
  }
}

extern "C" void kernel_launch(void* const* d_in, const int* in_sizes, int n_in,
                              void* d_out, int out_size, void* d_ws, size_t ws_size,
                              hipStream_t stream) {
  const float* beta   = (const float*)d_in[0];
  const float* x      = (const float*)d_in[1];
  const int*   oid    = (const int*)d_in[2];
  const float* energy = (const float*)d_in[3];
  const float* eph    = (const float*)d_in[4];
  const float* mom    = (const float*)d_in[5];
  const float* mph    = (const float*)d_in[6];
  const float* logits = (const float*)d_in[7];
  const int*   pid    = (const int*)d_in[8];
  float* outp = (float*)d_out;
  const int n = in_sizes[0];
  const int nhb = (n + HCH - 1) / HCH;      // 59 hit-chunks
  const int nblk_tot = nhb * NTILE;         // 944

  char* base = (char*)d_ws;
  size_t off = 0;
  uint*  ktab       = (uint*)(base + off);  off += (size_t)KOBJ * KTW * 4;
  float* cow_part   = (float*)(base + off); off += (size_t)GB * 4;
  float* pairs_part = (float*)(base + off); off += (size_t)nblk_tot * 4 * 4;
  float* scal_part  = (float*)(base + off); off += (size_t)MPREP * 8 * 4;
  unsigned* done_cnt = (unsigned*)(base + off); off += 256;
  off = (off + 255) & ~(size_t)255;
  unsigned long long* amax_part = (unsigned long long*)(base + off); off += (size_t)MPREP * KOBJ * 8;
  unsigned* cnt_part = (unsigned*)(base + off);                      off += (size_t)MPREP * KOBJ * 4;
  off = (off + 255) & ~(size_t)255;
  uint4* hry = (uint4*)(base + off); off += (size_t)nhb * HCH * 16;
  uint4* hrm = (uint4*)(base + off); off += (size_t)nhb * HCH * 16;

  k_prep<<<MPREP, 256, 0, stream>>>(beta, x, oid, energy, eph, mom, mph, logits, pid,
                                    amax_part, cnt_part, scal_part, hry, hrm,
                                    done_cnt, n);
  k_gather<<<GB, 256, 0, stream>>>(x, beta, amax_part, cnt_part, ktab, cow_part, n);
  k_pairs<<<dim3(nhb, NTILE), 256, 0, stream>>>(hry, hrm, ktab, scal_part, cow_part,
                                                pairs_part, done_cnt, outp, n);
}